// Round 1
// baseline (21.481 us; speedup 1.0000x reference)
//
#include <hip/hip_runtime.h>
#include <hip/hip_bf16.h>

#define NUM_USERS   16384
#define NUM_ITEMS   50000
#define EMBED_DIM   64
#define BATCH       16384
#define MAX_FRIENDS 32

// One 64-lane wave per batch element; lane index = embedding dimension.
// out[b] = <ue + (sum_f w_f * fe_f)/denom , ie>
__global__ __launch_bounds__(256) void bpr_kernel(
    const int* __restrict__ users,
    const int* __restrict__ items,
    const int* __restrict__ friends,
    const int* __restrict__ fcnt,
    const float* __restrict__ uemb,
    const float* __restrict__ iemb,
    const float* __restrict__ ufr,
    float* __restrict__ out)
{
    const int wave = threadIdx.x >> 6;            // 4 waves per block
    const int lane = threadIdx.x & 63;
    const int b = blockIdx.x * 4 + wave;
    if (b >= BATCH) return;

    const int u  = users[b];
    const int it = items[b];

    const float ie = iemb[(size_t)it * EMBED_DIM + lane];
    const float ue = uemb[(size_t)u  * EMBED_DIM + lane];
    const int   cnt = fcnt[u];

    // Lanes 0..31: friend id + masked user_friend weight.
    int   fid = 0;
    float w   = 0.0f;
    if (lane < MAX_FRIENDS) {
        fid = friends[(size_t)u * MAX_FRIENDS + lane];
        if (lane < cnt) {
            w = ufr[(size_t)u * NUM_USERS + fid];
        }
    }

    // acc[lane] = sum_f w_f * user_emb[fid_f][lane]
    float acc = 0.0f;
    #pragma unroll
    for (int f = 0; f < MAX_FRIENDS; ++f) {
        const int   idx = __shfl(fid, f);   // wave-uniform broadcast
        const float wf  = __shfl(w,   f);
        acc = fmaf(wf, uemb[(size_t)idx * EMBED_DIM + lane], acc);
    }

    const float denom = (float)max(cnt, 1);
    float v = (ue + acc / denom) * ie;

    // full-wave (64-lane) butterfly reduction
    #pragma unroll
    for (int off = 32; off > 0; off >>= 1)
        v += __shfl_xor(v, off);

    if (lane == 0) out[b] = v;
}

extern "C" void kernel_launch(void* const* d_in, const int* in_sizes, int n_in,
                              void* d_out, int out_size, void* d_ws, size_t ws_size,
                              hipStream_t stream) {
    const int*   users   = (const int*)  d_in[0];
    const int*   items   = (const int*)  d_in[1];
    const int*   friends = (const int*)  d_in[2];
    const int*   fcnt    = (const int*)  d_in[3];
    const float* uemb    = (const float*)d_in[4];
    const float* iemb    = (const float*)d_in[5];
    const float* ufr     = (const float*)d_in[6];
    float*       out     = (float*)d_out;

    const int blocks = BATCH / 4;   // 4 waves (batch elems) per 256-thread block
    bpr_kernel<<<blocks, 256, 0, stream>>>(users, items, friends, fcnt,
                                           uemb, iemb, ufr, out);
}

// Round 2
// 19.090 us; speedup vs baseline: 1.1252x; 1.1252x over previous
//
#include <hip/hip_runtime.h>
#include <hip/hip_bf16.h>

#define NUM_USERS   16384
#define NUM_ITEMS   50000
#define EMBED_DIM   64
#define BATCH       16384
#define MAX_FRIENDS 32

// One 64-lane wave per batch element.
// Lane = (g, q): g = lane>>4 selects one of 4 friend rows per iteration,
// q = lane&15 selects a float4 of the 64-dim embedding.
// out[b] = ( denom * <ue,ie> + sum_f w_f * <fe_f, ie> ) / denom
__global__ __launch_bounds__(256) void bpr_kernel(
    const int* __restrict__ users,
    const int* __restrict__ items,
    const int* __restrict__ friends,
    const int* __restrict__ fcnt,
    const float* __restrict__ uemb,
    const float* __restrict__ iemb,
    const float* __restrict__ ufr,
    float* __restrict__ out)
{
    const int wave = threadIdx.x >> 6;            // 4 waves per block
    const int lane = threadIdx.x & 63;
    const int b = blockIdx.x * 4 + wave;
    if (b >= BATCH) return;

    const int g = lane >> 4;      // friend sub-group 0..3
    const int q = lane & 15;      // dim quad 0..15

    const int u   = users[b];
    const int it  = items[b];
    const int cnt = fcnt[u];

    const float4 ie4 = *(const float4*)(iemb + (size_t)it * EMBED_DIM + q * 4);
    const float4 ue4 = *(const float4*)(uemb + (size_t)u  * EMBED_DIM + q * 4);

    // Lanes 0..31: friend id + masked user_friend weight (2-deep gather chain).
    int   fid = 0;
    float w   = 0.0f;
    if (lane < MAX_FRIENDS) {
        fid = friends[(size_t)u * MAX_FRIENDS + lane];
        if (lane < cnt) w = ufr[(size_t)u * NUM_USERS + fid];
    }

    // 8 iterations, 4 friend rows each -> 4 independent fma chains per lane.
    float4 acc = make_float4(0.f, 0.f, 0.f, 0.f);
    #pragma unroll
    for (int i = 0; i < 8; ++i) {
        const int   src = i * 4 + g;          // lane-variant src -> ds_bpermute
        const int   idx = __shfl(fid, src);
        const float wf  = __shfl(w,   src);
        const float4 a = *(const float4*)(uemb + (size_t)idx * EMBED_DIM + q * 4);
        acc.x = fmaf(wf, a.x, acc.x);
        acc.y = fmaf(wf, a.y, acc.y);
        acc.z = fmaf(wf, a.z, acc.z);
        acc.w = fmaf(wf, a.w, acc.w);
    }

    float v = acc.x * ie4.x + acc.y * ie4.y + acc.z * ie4.z + acc.w * ie4.w;

    const float denom = (float)max(cnt, 1);
    if (g == 0) {
        const float d = ue4.x * ie4.x + ue4.y * ie4.y + ue4.z * ie4.z + ue4.w * ie4.w;
        v = fmaf(denom, d, v);
    }

    // full-wave 64-lane butterfly reduction
    #pragma unroll
    for (int off = 32; off > 0; off >>= 1)
        v += __shfl_xor(v, off);

    if (lane == 0) out[b] = v / denom;
}

extern "C" void kernel_launch(void* const* d_in, const int* in_sizes, int n_in,
                              void* d_out, int out_size, void* d_ws, size_t ws_size,
                              hipStream_t stream) {
    const int*   users   = (const int*)  d_in[0];
    const int*   items   = (const int*)  d_in[1];
    const int*   friends = (const int*)  d_in[2];
    const int*   fcnt    = (const int*)  d_in[3];
    const float* uemb    = (const float*)d_in[4];
    const float* iemb    = (const float*)d_in[5];
    const float* ufr     = (const float*)d_in[6];
    float*       out     = (float*)d_out;

    const int blocks = BATCH / 4;   // 4 waves (batch elems) per 256-thread block
    bpr_kernel<<<blocks, 256, 0, stream>>>(users, items, friends, fcnt,
                                           uemb, iemb, ufr, out);
}